// Round 5
// baseline (418.964 us; speedup 1.0000x reference)
//
#include <hip/hip_runtime.h>
#include <math.h>

// BasicBlockA: masked conv (L*C) + bias + ELU -> grouped masked conv -> mean over L + residual.
// Mask: kernel row ky=2 always zero; row ky=1 keeps kx=0 always and kx=1 iff j<=i (42 live taps).
// R5: barrier-free latent loop. Each thread computes a 2-row x 4-col output chunk and
// recomputes its own h (3 h-rows x 6 cols x 3 ch) in registers from the LDS x tile.
// No h LDS round-trip, no __syncthreads in the loop (xs read-only after staging).
// Tile 64 rows x 32 cols per block, grid 512, __launch_bounds__(256,2) (grid-limited 2 blk/CU).

namespace {
constexpr int NC = 3, NH = 128, NW = 128, NL = 16;
constexpr int TW = 32, TH = 64;   // output tile: 64 rows x 32 cols
constexpr int XC = 36, XR = 66;   // xs: rows oy0-2..oy0+63, cols ox0-2..ox0+33, ch-interleaved
constexpr int WPL = 54;           // packed weights per latent: [i][j][ky<2][kx<3]
}

__device__ __forceinline__ float softplusf(float v) {
    return v > 20.f ? v : log1pf(expf(v));
}

// Build masked weights into d_ws: wb[0..863] = w1 packed, wb[864..1727] = w2 packed.
__global__ void prep_weights(const float* __restrict__ w1, const float* __restrict__ c1,
                             const float* __restrict__ w2, const float* __restrict__ c2,
                             float* __restrict__ wb) {
    int e = blockIdx.x * blockDim.x + threadIdx.x;
    if (e >= NL * NC * NC * 2 * 3) return;
    int kx = e % 3;
    int ky = (e / 3) % 2;
    int j  = (e / 6) % 3;
    int i  = (e / 18) % 3;
    int l  = e / WPL;
    int g = l * 81 + i * 27 + j * 9 + ky * 3 + kx;  // [L,C,C,3,3] global index
    bool used   = (ky == 0) || (kx == 0) || (kx == 1 && j <= i);
    bool center = (i == j) && (ky == 1) && (kx == 1);
    wb[e]       = used ? (center ? softplusf(c1[g]) : w1[g]) : 0.f;
    wb[864 + e] = used ? (center ? softplusf(c2[g]) : w2[g]) : 0.f;
}

__device__ __forceinline__ float eluf(float v) {
    float e = __expf(v) - 1.f;
    return v > 0.f ? v : e;
}

// load 24 consecutive floats (6 float4, 16B-aligned) from LDS
__device__ __forceinline__ void loadx24(float* __restrict__ d, const float* __restrict__ p) {
    const float4* q = (const float4*)p;
    float4 a = q[0], b = q[1], c = q[2], e = q[3], f = q[4], g = q[5];
    d[0]=a.x;  d[1]=a.y;  d[2]=a.z;  d[3]=a.w;
    d[4]=b.x;  d[5]=b.y;  d[6]=b.z;  d[7]=b.w;
    d[8]=c.x;  d[9]=c.y;  d[10]=c.z; d[11]=c.w;
    d[12]=e.x; d[13]=e.y; d[14]=e.z; d[15]=e.w;
    d[16]=f.x; d[17]=f.y; d[18]=f.z; d[19]=f.w;
    d[20]=g.x; d[21]=g.y; d[22]=g.z; d[23]=g.w;
}

// stage-1: h row (6 cols x 3 ch) from two x rows (24 floats each), masked ELU
__device__ __forceinline__ void stage1(float* __restrict__ h,
                                       const float* __restrict__ x0,  // x row hy-1 (ky=0)
                                       const float* __restrict__ x1,  // x row hy   (ky=1)
                                       const float* __restrict__ w,   // w1r[54]
                                       const float* __restrict__ br,
                                       float rmk, const float* __restrict__ cm) {
    #pragma unroll
    for (int c = 0; c < 6; ++c) {
        float pre[3];
        #pragma unroll
        for (int i = 0; i < 3; ++i) pre[i] = br[i];
        #pragma unroll
        for (int i = 0; i < 3; ++i)
        #pragma unroll
        for (int j = 0; j < 3; ++j)
        #pragma unroll
        for (int kx = 0; kx < 3; ++kx) {
            pre[i] += w[i*18 + j*6 + 0*3 + kx] * x0[(c + kx) * 3 + j];
            if (kx == 0 || (kx == 1 && j <= i))
                pre[i] += w[i*18 + j*6 + 1*3 + kx] * x1[(c + kx) * 3 + j];
        }
        float m = rmk * cm[c];
        #pragma unroll
        for (int i = 0; i < 3; ++i) h[c * 3 + i] = eluf(pre[i]) * m;
    }
}

// stage-2: accumulate one output row (3 ch x 4 px) from two h rows
__device__ __forceinline__ void stage2(float (*acc)[4],
                                       const float* __restrict__ hA,  // h row gy-1 (ky=0)
                                       const float* __restrict__ hB,  // h row gy   (ky=1)
                                       const float* __restrict__ w) { // w2r[54]
    #pragma unroll
    for (int i = 0; i < 3; ++i)
    #pragma unroll
    for (int j = 0; j < 3; ++j)
    #pragma unroll
    for (int kx = 0; kx < 3; ++kx) {
        float w0 = w[i*18 + j*6 + 0*3 + kx];
        #pragma unroll
        for (int p = 0; p < 4; ++p)
            acc[i][p] += w0 * hA[(p + kx) * 3 + j];
        if (kx == 0 || (kx == 1 && j <= i)) {
            float w1v = w[i*18 + j*6 + 1*3 + kx];
            #pragma unroll
            for (int p = 0; p < 4; ++p)
                acc[i][p] += w1v * hB[(p + kx) * 3 + j];
        }
    }
}

__global__ __launch_bounds__(256, 2) void fused_block(
    const float* __restrict__ x, const float* __restrict__ bias1,
    const float* __restrict__ res, const float* __restrict__ wb,
    float* __restrict__ out)
{
    __shared__ alignas(16) float xs[XR * XC * 3];  // 28512 B

    const int tid = threadIdx.x;
    const int b   = blockIdx.z;
    const int oy0 = blockIdx.y * TH;
    const int ox0 = blockIdx.x * TW;

    // ---- stage x tile once: coalesced global reads, ch-interleaved LDS ----
    const float* xb = x + b * NC * NH * NW;
    for (int idx = tid; idx < XR * XC * 3; idx += 256) {
        int c  = idx % XC;
        int r  = (idx / XC) % XR;
        int ch = idx / (XC * XR);
        int gy = oy0 - 2 + r, gx = ox0 - 2 + c;
        float v = 0.f;
        if (gy >= 0 && gy < NH && gx >= 0 && gx < NW)
            v = xb[ch * NH * NW + gy * NW + gx];
        xs[(r * XC + c) * 3 + ch] = v;
    }
    __syncthreads();  // the ONLY barrier

    // ---- thread's 2x4 output chunk ----
    const int rp = tid >> 3;        // row-pair 0..31 -> local out rows R0=2rp, R0+1
    const int u  = tid & 7;         // col chunk: global cols cs..cs+3, cs = ox0+4u
    const int R0 = 2 * rp;
    // local x/h row t maps to xs row t+2; thread's x cols start at cs-2 -> xs col 4u
    const float* xrow0 = &xs[(R0 * XC + 4 * u) * 3];  // local x row R0-2; +108 words per row

    // boundary masks (0/1 floats), once
    float rm[3], cm[6];
    #pragma unroll
    for (int k = 0; k < 3; ++k) {
        int gy = oy0 + R0 - 1 + k;
        rm[k] = (gy >= 0 && gy < NH) ? 1.f : 0.f;
    }
    #pragma unroll
    for (int c = 0; c < 6; ++c) {
        int gx = ox0 + 4 * u - 1 + c;
        cm[c] = (gx >= 0 && gx < NW) ? 1.f : 0.f;
    }

    float acc0[3][4] = {{0.f}}, acc1[3][4] = {{0.f}};

    #pragma unroll 1
    for (int l = 0; l < NL; ++l) {
        // wave-uniform weight loads -> SGPRs
        float w1r[WPL], w2r[WPL];
        #pragma unroll
        for (int i = 0; i < 3; ++i)
        #pragma unroll
        for (int j = 0; j < 3; ++j)
        #pragma unroll
        for (int ky = 0; ky < 2; ++ky)
        #pragma unroll
        for (int kx = 0; kx < 3; ++kx)
            if (ky == 0 || kx == 0 || (kx == 1 && j <= i)) {
                int o = i * 18 + j * 6 + ky * 3 + kx;
                w1r[o] = wb[l * WPL + o];
                w2r[o] = wb[864 + l * WPL + o];
            }
        float br[3];
        #pragma unroll
        for (int i = 0; i < 3; ++i) br[i] = bias1[l * 3 + i];

        float xr0[24], xr1[24], xr2[24], xr3[24];
        float h0[18], h1[18], h2[18];

        loadx24(xr0, xrow0 + 0 * XC * 3);       // x row R0-2
        loadx24(xr1, xrow0 + 1 * XC * 3);       // x row R0-1
        stage1(h0, xr0, xr1, w1r, br, rm[0], cm);   // h row R0-1
        loadx24(xr2, xrow0 + 2 * XC * 3);       // x row R0
        stage1(h1, xr1, xr2, w1r, br, rm[1], cm);   // h row R0
        stage2(acc0, h0, h1, w2r);                  // out row R0
        loadx24(xr3, xrow0 + 3 * XC * 3);       // x row R0+1
        stage1(h2, xr2, xr3, w1r, br, rm[2], cm);   // h row R0+1
        stage2(acc1, h1, h2, w2r);                  // out row R0+1
    }

    // ---- epilogue: out = acc/L + res*gate*x ----
    float rv = res[0];
    float rg = rv > 0.f ? rv : 0.f;
    float* ob = out + b * NC * NH * NW;
    #pragma unroll
    for (int k = 0; k < 2; ++k) {
        const int gy = oy0 + R0 + k;
        float (*acc)[4] = k ? acc1 : acc0;
        #pragma unroll
        for (int i = 0; i < 3; ++i) {
            float4 o;
            o.x = acc[i][0] * (1.f/16.f) + rg * xs[((R0 + k + 2) * XC + 4*u + 2 + 0) * 3 + i];
            o.y = acc[i][1] * (1.f/16.f) + rg * xs[((R0 + k + 2) * XC + 4*u + 2 + 1) * 3 + i];
            o.z = acc[i][2] * (1.f/16.f) + rg * xs[((R0 + k + 2) * XC + 4*u + 2 + 2) * 3 + i];
            o.w = acc[i][3] * (1.f/16.f) + rg * xs[((R0 + k + 2) * XC + 4*u + 2 + 3) * 3 + i];
            *(float4*)(ob + i * NH * NW + gy * NW + ox0 + 4 * u) = o;
        }
    }
}

extern "C" void kernel_launch(void* const* d_in, const int* in_sizes, int n_in,
                              void* d_out, int out_size, void* d_ws, size_t ws_size,
                              hipStream_t stream) {
    (void)in_sizes; (void)n_in; (void)out_size; (void)ws_size;
    const float* x   = (const float*)d_in[0];
    const float* w1  = (const float*)d_in[1];
    const float* c1  = (const float*)d_in[2];
    const float* b1  = (const float*)d_in[3];
    const float* w2  = (const float*)d_in[4];
    const float* c2  = (const float*)d_in[5];
    const float* res = (const float*)d_in[6];
    float* out = (float*)d_out;
    float* wb  = (float*)d_ws;  // 1728 floats of masked packed weights

    hipLaunchKernelGGL(prep_weights, dim3(4), dim3(256), 0, stream, w1, c1, w2, c2, wb);
    hipLaunchKernelGGL(fused_block, dim3(NW / TW, NH / TH, 64), dim3(256), 0, stream,
                       x, b1, res, wb, out);
}

// Round 6
// 173.966 us; speedup vs baseline: 2.4083x; 2.4083x over previous
//
#include <hip/hip_runtime.h>
#include <math.h>

// BasicBlockA: masked conv (L*C) + bias + ELU -> grouped masked conv -> mean over L + residual.
// Mask: kernel row ky=2 always zero; row ky=1 keeps kx=0 always and kx=1 iff j<=i (42 live taps).
// R6 = R4 skeleton (shared h through LDS, small per-thread state -> no spill) +
//   ping-pong hs buffers so only ONE barrier per latent is needed (stage2(l) and
//   stage1(l+1) use different buffers and may overlap). Barrier drains 32 -> 17 per block;
//   scheduler can mix stage-2 LDS reads with stage-1 FMAs inside each barrier interval.
// LDS 44.8KB -> 3 blocks/CU (pipe-bound, occupancy loss acceptable).

namespace {
constexpr int NC = 3, NH = 128, NW = 128, NL = 16;
constexpr int TILE = 32;
constexpr int XR = 34, XC = 40;  // x tile: rows (oy0-2 .. oy0+31), 40-col stride, 3ch interleaved
constexpr int HR = 33, HC = 36;  // h tile: rows (oy0-1 .. oy0+31), 36-col stride, 3ch interleaved
constexpr int HSZ = HR * HC * 3; // one h buffer, in floats
constexpr int WPL = 54;          // packed weights per latent: [i][j][ky<2][kx<3]
}

__device__ __forceinline__ float softplusf(float v) {
    return v > 20.f ? v : log1pf(expf(v));
}

// Build masked weights into d_ws: wb[0..863] = w1 packed, wb[864..1727] = w2 packed.
__global__ void prep_weights(const float* __restrict__ w1, const float* __restrict__ c1,
                             const float* __restrict__ w2, const float* __restrict__ c2,
                             float* __restrict__ wb) {
    int e = blockIdx.x * blockDim.x + threadIdx.x;
    if (e >= NL * NC * NC * 2 * 3) return;
    int kx = e % 3;
    int ky = (e / 3) % 2;
    int j  = (e / 6) % 3;
    int i  = (e / 18) % 3;
    int l  = e / WPL;
    int g = l * 81 + i * 27 + j * 9 + ky * 3 + kx;  // [L,C,C,3,3] global index
    bool used   = (ky == 0) || (kx == 0) || (kx == 1 && j <= i);
    bool center = (i == j) && (ky == 1) && (kx == 1);
    wb[e]       = used ? (center ? softplusf(c1[g]) : w1[g]) : 0.f;
    wb[864 + e] = used ? (center ? softplusf(c2[g]) : w2[g]) : 0.f;
}

__device__ __forceinline__ float eluf(float v) {
    float e = __expf(v) - 1.f;
    return v > 0.f ? v : e;
}

__global__ __launch_bounds__(256, 3) void fused_block(
    const float* __restrict__ x, const float* __restrict__ bias1,
    const float* __restrict__ res, const float* __restrict__ wb,
    float* __restrict__ out)
{
    __shared__ alignas(16) float xs[XR * XC * 3];
    __shared__ alignas(16) float hs[2][HSZ];   // ping-pong

    const int tid = threadIdx.x;
    const int b   = blockIdx.z;
    const int oy0 = blockIdx.y * TILE;
    const int ox0 = blockIdx.x * TILE;

    // ---- load x tile: planar (coalesced) global reads, channel-interleaved LDS store ----
    const float* xb = x + b * NC * NH * NW;
    for (int idx = tid; idx < XR * XC * 3; idx += 256) {
        int lx = idx % XC;
        int ly = (idx / XC) % XR;
        int c  = idx / (XC * XR);
        int gy = oy0 - 2 + ly, gx = ox0 - 2 + lx;
        float v = 0.f;
        if (gy >= 0 && gy < NH && gx >= 0 && gx < NW)
            v = xb[c * NH * NW + gy * NW + gx];
        xs[(ly * XC + lx) * 3 + c] = v;
    }

    // ---- stage-1 chunk map: A = 32 rows x 8 chunks; B = 41 edge chunks on wave 0 ----
    const int rA = tid >> 3;           // h row 0..31
    const int cA = (tid & 7) * 4;      // h col 0..28 step 4
    const bool hasB = (tid < 41);      // wave 0 only (waves 1-3 skip via execz)
    const int rB = (tid < 33) ? tid : 32;
    const int cB = (tid < 33) ? 32 : (tid - 33) * 4;

    // boundary masks as float 0/1, computed once
    float4 mA, mB;
    {
        int gyA = oy0 - 1 + rA;
        bool ra = (gyA >= 0 && gyA < NH);
        int gyB = oy0 - 1 + rB;
        bool rb = (gyB >= 0 && gyB < NH);
        int gxA = ox0 - 1 + cA, gxB = ox0 - 1 + cB;
        mA.x = (ra && gxA + 0 >= 0 && gxA + 0 < NW) ? 1.f : 0.f;
        mA.y = (ra && gxA + 1 >= 0 && gxA + 1 < NW) ? 1.f : 0.f;
        mA.z = (ra && gxA + 2 >= 0 && gxA + 2 < NW) ? 1.f : 0.f;
        mA.w = (ra && gxA + 3 >= 0 && gxA + 3 < NW) ? 1.f : 0.f;
        mB.x = (rb && gxB + 0 >= 0 && gxB + 0 < NW) ? 1.f : 0.f;
        mB.y = (rb && gxB + 1 >= 0 && gxB + 1 < NW) ? 1.f : 0.f;
        mB.z = (rb && gxB + 2 >= 0 && gxB + 2 < NW) ? 1.f : 0.f;
        mB.w = (rb && gxB + 3 >= 0 && gxB + 3 < NW) ? 1.f : 0.f;
    }

    const int ty = tid >> 3;       // output row within tile (0..31)
    const int tx = (tid & 7) * 4;  // output col, 1x4 chunk per thread

    // hoisted LDS word offsets (all chunks 16B-aligned)
    const int offA  = (rA * HC + cA) * 3;
    const int offB  = (rB * HC + cB) * 3;
    const int off20 = (ty * HC + tx) * 3;
    const int off21 = ((ty + 1) * HC + tx) * 3;
    const float* xA0 = &xs[(rA * XC + cA) * 3];
    const float* xA1 = &xs[((rA + 1) * XC + cA) * 3];
    const float* xB0 = &xs[(rB * XC + cB) * 3];
    const float* xB1 = &xs[((rB + 1) * XC + cB) * 3];

    float acc[3][4] = {{0.f}};

    __syncthreads();  // xs staged (first stage-1 runs before the in-loop barrier)

    #pragma unroll 1
    for (int l = 0; l < NL; ++l) {
        float* hbuf = hs[l & 1];
        float* hA   = hbuf + offA;
        float* hB   = hbuf + offB;
        const float* h20 = hbuf + off20;
        const float* h21 = hbuf + off21;

        // stage-1 weights (uniform index -> scalar loads); only live taps read
        float w1r[3][3][2][3];
        #pragma unroll
        for (int i = 0; i < 3; ++i)
        #pragma unroll
        for (int j = 0; j < 3; ++j)
        #pragma unroll
        for (int ky = 0; ky < 2; ++ky)
        #pragma unroll
        for (int kx = 0; kx < 3; ++kx)
            if (ky == 0 || kx == 0 || (kx == 1 && j <= i))
                w1r[i][j][ky][kx] = wb[l * WPL + i * 18 + j * 6 + ky * 3 + kx];
        float br[3];
        #pragma unroll
        for (int i = 0; i < 3; ++i) br[i] = bias1[l * 3 + i];

        // ---- stage 1, chunk A (all threads) -> hs[l&1] ----
        {
            float4 v0 = ((const float4*)xA0)[0], v1 = ((const float4*)xA0)[1];
            float4 v2 = ((const float4*)xA0)[2], v3 = ((const float4*)xA0)[3];
            float2 v4 = ((const float2*)xA0)[8];
            float4 u0 = ((const float4*)xA1)[0], u1 = ((const float4*)xA1)[1];
            float4 u2 = ((const float4*)xA1)[2], u3 = ((const float4*)xA1)[3];
            float x0[18] = {v0.x,v0.y,v0.z,v0.w,v1.x,v1.y,v1.z,v1.w,
                            v2.x,v2.y,v2.z,v2.w,v3.x,v3.y,v3.z,v3.w,v4.x,v4.y};
            float x1[16] = {u0.x,u0.y,u0.z,u0.w,u1.x,u1.y,u1.z,u1.w,
                            u2.x,u2.y,u2.z,u2.w,u3.x,u3.y,u3.z,u3.w};
            float pre[3][4];
            #pragma unroll
            for (int i = 0; i < 3; ++i)
                #pragma unroll
                for (int p = 0; p < 4; ++p) pre[i][p] = br[i];
            #pragma unroll
            for (int i = 0; i < 3; ++i)
            #pragma unroll
            for (int j = 0; j < 3; ++j)
            #pragma unroll
            for (int kx = 0; kx < 3; ++kx) {
                float w0 = w1r[i][j][0][kx];
                #pragma unroll
                for (int p = 0; p < 4; ++p)
                    pre[i][p] += w0 * x0[(kx + p) * 3 + j];
                if (kx == 0 || (kx == 1 && j <= i)) {
                    float w1v = w1r[i][j][1][kx];
                    #pragma unroll
                    for (int p = 0; p < 4; ++p)
                        pre[i][p] += w1v * x1[(kx + p) * 3 + j];
                }
            }
            float m[4] = {mA.x, mA.y, mA.z, mA.w};
            float hv[12];
            #pragma unroll
            for (int p = 0; p < 4; ++p)
                #pragma unroll
                for (int i = 0; i < 3; ++i)
                    hv[p * 3 + i] = eluf(pre[i][p]) * m[p];
            ((float4*)hA)[0] = make_float4(hv[0], hv[1], hv[2],  hv[3]);
            ((float4*)hA)[1] = make_float4(hv[4], hv[5], hv[6],  hv[7]);
            ((float4*)hA)[2] = make_float4(hv[8], hv[9], hv[10], hv[11]);
        }
        // ---- stage 1, chunk B: tid<41, wave 0 only ----
        if (hasB) {
            float4 v0 = ((const float4*)xB0)[0], v1 = ((const float4*)xB0)[1];
            float4 v2 = ((const float4*)xB0)[2], v3 = ((const float4*)xB0)[3];
            float2 v4 = ((const float2*)xB0)[8];
            float4 u0 = ((const float4*)xB1)[0], u1 = ((const float4*)xB1)[1];
            float4 u2 = ((const float4*)xB1)[2], u3 = ((const float4*)xB1)[3];
            float x0[18] = {v0.x,v0.y,v0.z,v0.w,v1.x,v1.y,v1.z,v1.w,
                            v2.x,v2.y,v2.z,v2.w,v3.x,v3.y,v3.z,v3.w,v4.x,v4.y};
            float x1[16] = {u0.x,u0.y,u0.z,u0.w,u1.x,u1.y,u1.z,u1.w,
                            u2.x,u2.y,u2.z,u2.w,u3.x,u3.y,u3.z,u3.w};
            float pre[3][4];
            #pragma unroll
            for (int i = 0; i < 3; ++i)
                #pragma unroll
                for (int p = 0; p < 4; ++p) pre[i][p] = br[i];
            #pragma unroll
            for (int i = 0; i < 3; ++i)
            #pragma unroll
            for (int j = 0; j < 3; ++j)
            #pragma unroll
            for (int kx = 0; kx < 3; ++kx) {
                float w0 = w1r[i][j][0][kx];
                #pragma unroll
                for (int p = 0; p < 4; ++p)
                    pre[i][p] += w0 * x0[(kx + p) * 3 + j];
                if (kx == 0 || (kx == 1 && j <= i)) {
                    float w1v = w1r[i][j][1][kx];
                    #pragma unroll
                    for (int p = 0; p < 4; ++p)
                        pre[i][p] += w1v * x1[(kx + p) * 3 + j];
                }
            }
            float m[4] = {mB.x, mB.y, mB.z, mB.w};
            float hv[12];
            #pragma unroll
            for (int p = 0; p < 4; ++p)
                #pragma unroll
                for (int i = 0; i < 3; ++i)
                    hv[p * 3 + i] = eluf(pre[i][p]) * m[p];
            ((float4*)hB)[0] = make_float4(hv[0], hv[1], hv[2],  hv[3]);
            ((float4*)hB)[1] = make_float4(hv[4], hv[5], hv[6],  hv[7]);
            ((float4*)hB)[2] = make_float4(hv[8], hv[9], hv[10], hv[11]);
        }

        // stage-2 weights: scalar loads issued before the barrier
        float w2r[3][3][2][3];
        #pragma unroll
        for (int i = 0; i < 3; ++i)
        #pragma unroll
        for (int j = 0; j < 3; ++j)
        #pragma unroll
        for (int ky = 0; ky < 2; ++ky)
        #pragma unroll
        for (int kx = 0; kx < 3; ++kx)
            if (ky == 0 || kx == 0 || (kx == 1 && j <= i))
                w2r[i][j][ky][kx] = wb[864 + l * WPL + i * 18 + j * 6 + ky * 3 + kx];

        __syncthreads();  // the ONLY in-loop barrier: hs[l&1] fully written

        // ---- stage 2: acc += conv(h, w2[l]); may overlap next stage-1 (other buffer) ----
        {
            float4 v0 = ((const float4*)h20)[0], v1 = ((const float4*)h20)[1];
            float4 v2 = ((const float4*)h20)[2], v3 = ((const float4*)h20)[3];
            float2 v4 = ((const float2*)h20)[8];
            float4 u0 = ((const float4*)h21)[0], u1 = ((const float4*)h21)[1];
            float4 u2 = ((const float4*)h21)[2], u3 = ((const float4*)h21)[3];
            float h0[18] = {v0.x,v0.y,v0.z,v0.w,v1.x,v1.y,v1.z,v1.w,
                            v2.x,v2.y,v2.z,v2.w,v3.x,v3.y,v3.z,v3.w,v4.x,v4.y};
            float h1[16] = {u0.x,u0.y,u0.z,u0.w,u1.x,u1.y,u1.z,u1.w,
                            u2.x,u2.y,u2.z,u2.w,u3.x,u3.y,u3.z,u3.w};
            #pragma unroll
            for (int i = 0; i < 3; ++i)
            #pragma unroll
            for (int j = 0; j < 3; ++j)
            #pragma unroll
            for (int kx = 0; kx < 3; ++kx) {
                float w0 = w2r[i][j][0][kx];
                #pragma unroll
                for (int p = 0; p < 4; ++p)
                    acc[i][p] += w0 * h0[(kx + p) * 3 + j];
                if (kx == 0 || (kx == 1 && j <= i)) {
                    float w1v = w2r[i][j][1][kx];
                    #pragma unroll
                    for (int p = 0; p < 4; ++p)
                        acc[i][p] += w1v * h1[(kx + p) * 3 + j];
                }
            }
        }
    }

    // ---- epilogue: out = acc/L + res*gate*x ----
    float rv = res[0];
    float rg = rv > 0.f ? rv : 0.f;
    const int gy = oy0 + ty;
    float* ob = out + b * NC * NH * NW;
    #pragma unroll
    for (int i = 0; i < 3; ++i) {
        float4 o;
        o.x = acc[i][0] * (1.f / 16.f) + rg * xs[((ty + 2) * XC + tx + 2 + 0) * 3 + i];
        o.y = acc[i][1] * (1.f / 16.f) + rg * xs[((ty + 2) * XC + tx + 2 + 1) * 3 + i];
        o.z = acc[i][2] * (1.f / 16.f) + rg * xs[((ty + 2) * XC + tx + 2 + 2) * 3 + i];
        o.w = acc[i][3] * (1.f / 16.f) + rg * xs[((ty + 2) * XC + tx + 2 + 3) * 3 + i];
        *(float4*)(ob + i * NH * NW + gy * NW + ox0 + tx) = o;
    }
}

extern "C" void kernel_launch(void* const* d_in, const int* in_sizes, int n_in,
                              void* d_out, int out_size, void* d_ws, size_t ws_size,
                              hipStream_t stream) {
    (void)in_sizes; (void)n_in; (void)out_size; (void)ws_size;
    const float* x   = (const float*)d_in[0];
    const float* w1  = (const float*)d_in[1];
    const float* c1  = (const float*)d_in[2];
    const float* b1  = (const float*)d_in[3];
    const float* w2  = (const float*)d_in[4];
    const float* c2  = (const float*)d_in[5];
    const float* res = (const float*)d_in[6];
    float* out = (float*)d_out;
    float* wb  = (float*)d_ws;  // 1728 floats of masked packed weights

    hipLaunchKernelGGL(prep_weights, dim3(4), dim3(256), 0, stream, w1, c1, w2, c2, wb);
    hipLaunchKernelGGL(fused_block, dim3(4, 4, 64), dim3(256), 0, stream,
                       x, b1, res, wb, out);
}